// Round 4
// baseline (302.866 us; speedup 1.0000x reference)
//
#include <hip/hip_runtime.h>
#include <hip/hip_bf16.h>

#define NN 200000
#define D 128
#define P 4096
#define R 4
#define T 3
#define K 16
#define NPB 4   // pairs per block (cross-pair software pipeline)

__device__ __forceinline__ float bf2f(unsigned int u) {
    union { unsigned int i; float f; } c;
    c.i = u << 16;
    return c.f;
}
__device__ __forceinline__ unsigned short f2bf(float x) {  // RNE
    union { float f; unsigned int i; } c; c.f = x;
    unsigned int r = c.i + 0x7FFFu + ((c.i >> 16) & 1u);
    return (unsigned short)(r >> 16);
}
__device__ __forceinline__ float ldE(const void* p, size_t i, int f32) {
    return f32 ? ((const float*)p)[i] : bf2f(((const unsigned short*)p)[i]);
}
__device__ __forceinline__ void ld8(const void* p, size_t off, int f32, float* o) {
    if (f32) {
        const float* q = (const float*)p + off;
        float4 a = *(const float4*)q;
        float4 b = *(const float4*)(q + 4);
        o[0]=a.x; o[1]=a.y; o[2]=a.z; o[3]=a.w;
        o[4]=b.x; o[5]=b.y; o[6]=b.z; o[7]=b.w;
    } else {
        uint4 r = *(const uint4*)((const unsigned short*)p + off);
        o[0]=bf2f(r.x & 0xffffu); o[1]=bf2f(r.x >> 16);
        o[2]=bf2f(r.y & 0xffffu); o[3]=bf2f(r.y >> 16);
        o[4]=bf2f(r.z & 0xffffu); o[5]=bf2f(r.z >> 16);
        o[6]=bf2f(r.w & 0xffffu); o[7]=bf2f(r.w >> 16);
    }
}

// LDS-only barrier: orders ds ops without draining vmcnt, so cross-pair
// prefetch loads stay in flight across it (m194-m201 verified pattern).
// All inter-wave communication in fused_all is through LDS -> lgkmcnt(0)
// before s_barrier is sufficient for correctness.
__device__ __forceinline__ void lbar() {
    asm volatile("s_waitcnt lgkmcnt(0)" ::: "memory");
    __builtin_amdgcn_s_barrier();
    asm volatile("" ::: "memory");
}

// Prep kernel: per-block dtype detection + v_t/u_t precompute. Grid = T blocks x 128.
__global__ void prep_kernel(const unsigned short* __restrict__ emb_u,
                            const void* __restrict__ W_phi,
                            const void* __restrict__ W_zeta,
                            int* __restrict__ gflag,
                            float* __restrict__ ws_v, float* __restrict__ ws_u) {
    __shared__ int sbad[2];
    const int tid = threadIdx.x;          // 0..127
    const int t   = blockIdx.x;           // 0..T-1
    // dtype sniff: even-index ushorts of bf16(N(0,1)) have small exponents;
    // of fp32 they are random mantissa bits -> uniform exponents. (validated r2-r5)
    int bad = 0;
    #pragma unroll
    for (int i = 0; i < 4; ++i) {
        unsigned short u = emb_u[(size_t)(blockIdx.x * 512 + tid * 4 + i) * 2 * 97];
        unsigned int e = (u >> 7) & 0xFFu;
        if (e >= 147u) bad = 1;
    }
    int anyb = __any(bad) ? 1 : 0;
    if ((tid & 63) == 0) sbad[tid >> 6] = anyb;
    __syncthreads();
    const int f32 = sbad[0] | sbad[1];
    if (t == 0 && tid == 0) *gflag = f32;

    const int d = tid;
    const size_t rb = (size_t)(t * D + d) * D;
    float av = 0.f, au = 0.f;
    for (int e = 0; e < D; e += 8) {
        float w[8], zn[8], zs[8];
        ld8(W_phi, rb + e, f32, w);
        ld8(W_zeta, e, f32, zn);
        ld8(W_zeta, D + e, f32, zs);
        #pragma unroll
        for (int q = 0; q < 8; ++q) { av += w[q] * zn[q]; au += w[q] * zs[q]; }
    }
    ws_v[t * D + d] = av;
    ws_u[t * D + d] = au;
}

// Fused kernel v5: block = NPB pairs x 8 waves; wave = (side, r). Cross-pair
// software pipeline: pair t+1's index loads issue at iteration top (fly during
// es/scores of t), its row gathers issue after gsum (fly during beta/epilogue
// of t). Inner barriers are lgkm-only so prefetch survives them. v4's flaw
// (one gather burst then a long dry compute phase -> ~18 lines/CU in flight)
// becomes a steady issue stream.
__global__ __launch_bounds__(512, 3) void fused_all(
    const void* __restrict__ emb,               // (N,D)
    const int* __restrict__ pairs,              // (P,2)
    const int* __restrict__ types,              // (N,)
    const int* __restrict__ nbr,                // (P,2,R,K)
    const void* __restrict__ dlt,               // (P,2,R,K)
    const void* __restrict__ W_bw,              // (R,D,D)
    const void* __restrict__ W_bb,              // (R,D)
    const float* __restrict__ ws_v,             // (T,D) fp32
    const float* __restrict__ ws_u,             // (T,D) fp32
    const int* __restrict__ flag,
    void* __restrict__ out)                     // (P,D)
{
    __shared__ __align__(16) float vsh[T * D];
    __shared__ __align__(16) float ush[T * D];
    __shared__ __align__(16) float gsh[2][R][D];   // [s][r][d]      4 KB
    __shared__ __align__(16) float gsum[R][D];     // sum over s     2 KB
    __shared__ __align__(16) float ysh[R][D];      // per-r y        2 KB
    __shared__ __align__(16) float bsh[D];         // sum_r W_bb[r]  0.5 KB

    const int f32  = *flag;
    const int tid  = threadIdx.x;
    const int wv   = tid >> 6;                  // 0..7
    const int l    = tid & 63;
    const int s    = wv >> 2;                   // side
    const int r    = wv & 3;                    // relation
    const int rsub = l >> 4;                    // quarter-wave
    const int ch   = l & 15;                    // 16B (8-elem) chunk within a row
    const int k    = l & 15;                    // neighbor slot owned by lane
    const int p0   = blockIdx.x * NPB;
    const unsigned short* eu = (const unsigned short*)emb;

    // ---- Prologue: pair p0 full prefetch (index chase + gathers), then LDS
    // table fill overlapping the in-flight loads.
    int   nb, ns, tp, ts;
    float dtv, ee0, ee1;
    uint4 cur[4] = {};
    {
        const int base0 = p0 * 2 * R * K + s * R * K + r * K;
        nb  = nbr[base0 + k];
        dtv = ldE(dlt, (size_t)(base0 + k), f32);
        ns  = pairs[p0 * 2 + s];
        tp  = types[nb];
        ts  = types[ns];
        if (!f32) {
            int snb_[4];
            #pragma unroll
            for (int i = 0; i < 4; ++i) snb_[i] = __shfl(nb, i * 4 + rsub, 64);
            #pragma unroll
            for (int i = 0; i < 4; ++i)
                cur[i] = *(const uint4*)(eu + (size_t)snb_[i] * D + ch * 8);
            unsigned int w2 = *(const unsigned int*)(eu + (size_t)ns * D + 2 * l);
            ee0 = bf2f(w2 & 0xffffu); ee1 = bf2f(w2 >> 16);
        } else {
            float2 f2 = *(const float2*)((const float*)emb + (size_t)ns * D + 2 * l);
            ee0 = f2.x; ee1 = f2.y;
        }
    }
    for (int i = tid; i < T * D; i += 512) { vsh[i] = ws_v[i]; ush[i] = ws_u[i]; }
    if (tid < D) {
        float b = 0.f;
        #pragma unroll
        for (int rr = 0; rr < R; ++rr) b += ldE(W_bb, (size_t)rr * D + tid, f32);
        bsh[tid] = b;
    }
    __syncthreads();

    for (int t = 0; t < NPB; ++t) {
        const int p = p0 + t;

        // ---- Stage-1 prefetch for pair t+1: independent index loads.
        int nb2 = 0, ns2 = 0; float dtv2 = 0.f;
        if (t < NPB - 1) {
            const int base2 = (p + 1) * 2 * R * K + s * R * K + r * K;
            nb2  = nbr[base2 + k];
            dtv2 = ldE(dlt, (size_t)(base2 + k), f32);
            ns2  = pairs[(p + 1) * 2 + s];
        }

        // ---- Side score e_s = emb[pair_s] . u_{type}.
        float es;
        {
            float a = ee0 * ush[ts * D + 2 * l] + ee1 * ush[ts * D + 2 * l + 1];
            #pragma unroll
            for (int off = 1; off <= 32; off <<= 1) a += __shfl_xor(a, off, 64);
            es = a;
        }

        float sdt[4]; int stp[4];
        #pragma unroll
        for (int i = 0; i < 4; ++i) {
            sdt[i] = __shfl(dtv, i * 4 + rsub, 64);
            stp[i] = __shfl(tp,  i * 4 + rsub, 64);
        }

        // ---- Scores e_n = emb[nbr] . v_{type} (16-lane group reduce).
        float ef[4];
        if (!f32) {
            #pragma unroll
            for (int i = 0; i < 4; ++i) {
                const float* vp = vsh + stp[i] * D + ch * 8;
                float4 v0 = *(const float4*)vp;
                float4 v1 = *(const float4*)(vp + 4);
                float a = 0.f;
                a += bf2f(cur[i].x & 0xffffu) * v0.x + bf2f(cur[i].x >> 16) * v0.y;
                a += bf2f(cur[i].y & 0xffffu) * v0.z + bf2f(cur[i].y >> 16) * v0.w;
                a += bf2f(cur[i].z & 0xffffu) * v1.x + bf2f(cur[i].z >> 16) * v1.y;
                a += bf2f(cur[i].w & 0xffffu) * v1.z + bf2f(cur[i].w >> 16) * v1.w;
                #pragma unroll
                for (int off = 1; off <= 8; off <<= 1) a += __shfl_xor(a, off, 64);
                ef[i] = (a + es) * __expf(-sdt[i]);
            }
        } else {
            int snbL[4];
            #pragma unroll
            for (int i = 0; i < 4; ++i) snbL[i] = __shfl(nb, i * 4 + rsub, 64);
            #pragma unroll
            for (int i = 0; i < 4; ++i) {
                const float* vp = vsh + stp[i] * D + ch * 8;
                float rv[8];
                ld8(emb, (size_t)snbL[i] * D + ch * 8, 1, rv);
                float a = 0.f;
                #pragma unroll
                for (int q = 0; q < 8; ++q) a += rv[q] * vp[q];
                #pragma unroll
                for (int off = 1; off <= 8; off <<= 1) a += __shfl_xor(a, off, 64);
                ef[i] = (a + es) * __expf(-sdt[i]);
            }
        }

        // ---- Softmax over the 16 rows of (s,r).
        float m = fmaxf(fmaxf(ef[0], ef[1]), fmaxf(ef[2], ef[3]));
        m = fmaxf(m, __shfl_xor(m, 16, 64));
        m = fmaxf(m, __shfl_xor(m, 32, 64));
        float al[4], ssum = 0.f;
        #pragma unroll
        for (int i = 0; i < 4; ++i) { al[i] = __expf(ef[i] - m); ssum += al[i]; }
        ssum += __shfl_xor(ssum, 16, 64);
        ssum += __shfl_xor(ssum, 32, 64);
        float inv = 1.f / ssum;

        // ---- Alpha-weighted sum.
        float acc[8] = {0.f,0.f,0.f,0.f,0.f,0.f,0.f,0.f};
        if (!f32) {
            #pragma unroll
            for (int i = 0; i < 4; ++i) {
                float a = al[i] * inv;
                acc[0] += a * bf2f(cur[i].x & 0xffffu); acc[1] += a * bf2f(cur[i].x >> 16);
                acc[2] += a * bf2f(cur[i].y & 0xffffu); acc[3] += a * bf2f(cur[i].y >> 16);
                acc[4] += a * bf2f(cur[i].z & 0xffffu); acc[5] += a * bf2f(cur[i].z >> 16);
                acc[6] += a * bf2f(cur[i].w & 0xffffu); acc[7] += a * bf2f(cur[i].w >> 16);
            }
        } else {
            int snbL[4];
            #pragma unroll
            for (int i = 0; i < 4; ++i) snbL[i] = __shfl(nb, i * 4 + rsub, 64);
            #pragma unroll
            for (int i = 0; i < 4; ++i) {
                float a = al[i] * inv;
                float rv[8];
                ld8(emb, (size_t)snbL[i] * D + ch * 8, 1, rv);
                #pragma unroll
                for (int q = 0; q < 8; ++q) acc[q] += a * rv[q];
            }
        }
        #pragma unroll
        for (int q = 0; q < 8; ++q) {
            acc[q] += __shfl_xor(acc[q], 16, 64);
            acc[q] += __shfl_xor(acc[q], 32, 64);
        }
        if (rsub == 0) {
            *(float4*)(&gsh[s][r][ch * 8])     = make_float4(acc[0], acc[1], acc[2], acc[3]);
            *(float4*)(&gsh[s][r][ch * 8 + 4]) = make_float4(acc[4], acc[5], acc[6], acc[7]);
        }
        lbar();

        // gsum[r][d] = gsh[0][r][d] + gsh[1][r][d]; 512 threads = R*D exactly.
        {
            const int r2 = tid >> 7, d2 = tid & 127;
            gsum[r2][d2] = gsh[0][r2][d2] + gsh[1][r2][d2];
        }
        lbar();

        // ---- Stage-2 prefetch for pair t+1: dependent loads (need nb2/ns2,
        // which have had the es+scores+softmax phases to land). The gathers
        // fly through beta + epilogue + next iteration's es.
        int tp2 = 0, ts2 = 0; float ee20 = 0.f, ee21 = 0.f;
        uint4 cur2[4] = {};
        if (t < NPB - 1) {
            tp2 = types[nb2];
            ts2 = types[ns2];
            if (!f32) {
                int snb2[4];
                #pragma unroll
                for (int i = 0; i < 4; ++i) snb2[i] = __shfl(nb2, i * 4 + rsub, 64);
                #pragma unroll
                for (int i = 0; i < 4; ++i)
                    cur2[i] = *(const uint4*)(eu + (size_t)snb2[i] * D + ch * 8);
                unsigned int w2 = *(const unsigned int*)(eu + (size_t)ns2 * D + 2 * l);
                ee20 = bf2f(w2 & 0xffffu); ee21 = bf2f(w2 >> 16);
            } else {
                float2 f2 = *(const float2*)((const float*)emb + (size_t)ns2 * D + 2 * l);
                ee20 = f2.x; ee21 = f2.y;
            }
        }

        // ---- Beta matvec: wave (s,r) computes y_r[e] for e in [s*64, s*64+64).
        float y[8] = {0.f,0.f,0.f,0.f,0.f,0.f,0.f,0.f};
        const int ch8  = l & 7;
        const int dgrp = l >> 3;
        const unsigned short* Wu = (const unsigned short*)W_bw;
        #pragma unroll 4
        for (int dd = 0; dd < 16; ++dd) {
            const int d = dgrp * 16 + ((dd + 2 * dgrp) & 15);
            const float gd = gsum[r][d];
            const size_t wo = ((size_t)(r * D + d)) * D + s * 64 + ch8 * 8;
            if (!f32) {
                uint4 wr = *(const uint4*)(Wu + wo);
                y[0] += gd * bf2f(wr.x & 0xffffu); y[1] += gd * bf2f(wr.x >> 16);
                y[2] += gd * bf2f(wr.y & 0xffffu); y[3] += gd * bf2f(wr.y >> 16);
                y[4] += gd * bf2f(wr.z & 0xffffu); y[5] += gd * bf2f(wr.z >> 16);
                y[6] += gd * bf2f(wr.w & 0xffffu); y[7] += gd * bf2f(wr.w >> 16);
            } else {
                float wb[8]; ld8(W_bw, wo, 1, wb);
                #pragma unroll
                for (int q = 0; q < 8; ++q) y[q] += gd * wb[q];
            }
        }
        #pragma unroll
        for (int q = 0; q < 8; ++q) {
            y[q] += __shfl_xor(y[q], 8, 64);
            y[q] += __shfl_xor(y[q], 16, 64);
            y[q] += __shfl_xor(y[q], 32, 64);
        }
        if (dgrp == 0) {
            *(float4*)(&ysh[r][s * 64 + ch8 * 8])     = make_float4(y[0], y[1], y[2], y[3]);
            *(float4*)(&ysh[r][s * 64 + ch8 * 8 + 4]) = make_float4(y[4], y[5], y[6], y[7]);
        }
        lbar();

        // ---- Epilogue: wave 0, lanes 0..15 (16 lanes -> 256B store).
        if (wv == 0 && l < 16) {
            const int c = l;
            float o[8];
            #pragma unroll
            for (int q = 0; q < 8; ++q) {
                const int e = c * 8 + q;
                float x = (ysh[0][e] + ysh[1][e] + ysh[2][e] + ysh[3][e]
                           + 2.f * bsh[e]) * 0.125f;
                o[q] = 1.f / (1.f + __expf(-x));
            }
            size_t ob = (size_t)p * D + c * 8;
            if (f32) {
                *(float4*)((float*)out + ob)     = make_float4(o[0], o[1], o[2], o[3]);
                *(float4*)((float*)out + ob + 4) = make_float4(o[4], o[5], o[6], o[7]);
            } else {
                uint4 pk;
                pk.x = (unsigned int)f2bf(o[0]) | ((unsigned int)f2bf(o[1]) << 16);
                pk.y = (unsigned int)f2bf(o[2]) | ((unsigned int)f2bf(o[3]) << 16);
                pk.z = (unsigned int)f2bf(o[4]) | ((unsigned int)f2bf(o[5]) << 16);
                pk.w = (unsigned int)f2bf(o[6]) | ((unsigned int)f2bf(o[7]) << 16);
                *(uint4*)((unsigned short*)out + ob) = pk;
            }
        }
        lbar();   // WAR: ysh/gsum/gsh reused next iteration

        // ---- Rotate prefetched state.
        if (t < NPB - 1) {
            nb = nb2; dtv = dtv2; ns = ns2; tp = tp2; ts = ts2;
            ee0 = ee20; ee1 = ee21;
            #pragma unroll
            for (int i = 0; i < 4; ++i) cur[i] = cur2[i];
        }
    }
}

extern "C" void kernel_launch(void* const* d_in, const int* in_sizes, int n_in,
                              void* d_out, int out_size, void* d_ws, size_t ws_size,
                              hipStream_t stream) {
    const void* emb    = d_in[0];
    const int*  pairs  = (const int*)d_in[1];
    const int*  types  = (const int*)d_in[2];
    const int*  nbr    = (const int*)d_in[3];
    const void* dlt    = d_in[4];
    const void* W_phi  = d_in[5];
    const void* W_zeta = d_in[6];
    const void* W_bw   = d_in[7];
    const void* W_bb   = d_in[8];

    int*   flag = (int*)d_ws;                        // bytes [0,256)
    float* ws_v = (float*)d_ws + 64;                 // 384 floats
    float* ws_u = ws_v + T * D;                      // 384 floats

    prep_kernel<<<dim3(T), dim3(128), 0, stream>>>((const unsigned short*)emb,
                                                   W_phi, W_zeta, flag, ws_v, ws_u);
    fused_all<<<dim3(P / NPB), dim3(512), 0, stream>>>(emb, pairs, types, nbr, dlt,
                                                       W_bw, W_bb, ws_v, ws_u, flag, d_out);
}

// Round 6
// 292.475 us; speedup vs baseline: 1.0355x; 1.0355x over previous
//
#include <hip/hip_runtime.h>
#include <hip/hip_bf16.h>

#define NN 200000
#define D 128
#define P 4096
#define R 4
#define T 3
#define K 16

__device__ __forceinline__ float bf2f(unsigned int u) {
    union { unsigned int i; float f; } c;
    c.i = u << 16;
    return c.f;
}
__device__ __forceinline__ unsigned short f2bf(float x) {  // RNE
    union { float f; unsigned int i; } c; c.f = x;
    unsigned int r = c.i + 0x7FFFu + ((c.i >> 16) & 1u);
    return (unsigned short)(r >> 16);
}
__device__ __forceinline__ float ldE(const void* p, size_t i, int f32) {
    return f32 ? ((const float*)p)[i] : bf2f(((const unsigned short*)p)[i]);
}
__device__ __forceinline__ void ld8(const void* p, size_t off, int f32, float* o) {
    if (f32) {
        const float* q = (const float*)p + off;
        float4 a = *(const float4*)q;
        float4 b = *(const float4*)(q + 4);
        o[0]=a.x; o[1]=a.y; o[2]=a.z; o[3]=a.w;
        o[4]=b.x; o[5]=b.y; o[6]=b.z; o[7]=b.w;
    } else {
        uint4 r = *(const uint4*)((const unsigned short*)p + off);
        o[0]=bf2f(r.x & 0xffffu); o[1]=bf2f(r.x >> 16);
        o[2]=bf2f(r.y & 0xffffu); o[3]=bf2f(r.y >> 16);
        o[4]=bf2f(r.z & 0xffffu); o[5]=bf2f(r.z >> 16);
        o[6]=bf2f(r.w & 0xffffu); o[7]=bf2f(r.w >> 16);
    }
}

// Prep kernel: per-block dtype detection + v_t/u_t precompute. Grid = T blocks x 128.
__global__ void prep_kernel(const unsigned short* __restrict__ emb_u,
                            const void* __restrict__ W_phi,
                            const void* __restrict__ W_zeta,
                            int* __restrict__ gflag,
                            float* __restrict__ ws_v, float* __restrict__ ws_u) {
    __shared__ int sbad[2];
    const int tid = threadIdx.x;          // 0..127
    const int t   = blockIdx.x;           // 0..T-1
    // dtype sniff: even-index ushorts of bf16(N(0,1)) have small exponents;
    // of fp32 they are random mantissa bits -> uniform exponents. (validated r2-r5)
    int bad = 0;
    #pragma unroll
    for (int i = 0; i < 4; ++i) {
        unsigned short u = emb_u[(size_t)(blockIdx.x * 512 + tid * 4 + i) * 2 * 97];
        unsigned int e = (u >> 7) & 0xFFu;
        if (e >= 147u) bad = 1;
    }
    int anyb = __any(bad) ? 1 : 0;
    if ((tid & 63) == 0) sbad[tid >> 6] = anyb;
    __syncthreads();
    const int f32 = sbad[0] | sbad[1];
    if (t == 0 && tid == 0) *gflag = f32;

    const int d = tid;
    const size_t rb = (size_t)(t * D + d) * D;
    float av = 0.f, au = 0.f;
    for (int e = 0; e < D; e += 8) {
        float w[8], zn[8], zs[8];
        ld8(W_phi, rb + e, f32, w);
        ld8(W_zeta, e, f32, zn);
        ld8(W_zeta, D + e, f32, zs);
        #pragma unroll
        for (int q = 0; q < 8; ++q) { av += w[q] * zn[q]; au += w[q] * zs[q]; }
    }
    ws_v[t * D + d] = av;
    ws_u[t * D + d] = au;
}

// Fused kernel v6: v1's proven structure (block = 2 pairs x 2 sides; wave =
// (pair, side); 4-iteration r-loop with depth-1 gather prefetch) at FULL
// occupancy. Empirically this compiler's 2nd __launch_bounds__ arg = blocks/CU
// (validated r2-r4); v1's (256,4) capped it at 16 waves/CU and it measured 42%
// -- at its own cap. (256,8) -> 32 waves/CU (HW max), VGPR cap 64 (v1 used 52),
// grid 2048 = exactly 8 blocks/CU -> whole grid resident.
// Also carried (validated): pre-barrier hoist of first gathers + e_s row;
// fp32 path reloads rows (no rv[4][8] held across softmax); beta-phase
// staggered gsh reads (kills 4-way bank conflict).
__global__ __launch_bounds__(256, 8) void fused_all(
    const void* __restrict__ emb,               // (N,D)
    const int* __restrict__ pairs,              // (P,2)
    const int* __restrict__ types,              // (N,)
    const int* __restrict__ nbr,                // (P,2,R,K)
    const void* __restrict__ dlt,               // (P,2,R,K)
    const void* __restrict__ W_bw,              // (R,D,D)
    const void* __restrict__ W_bb,              // (R,D)
    const float* __restrict__ ws_v,             // (T,D) fp32
    const float* __restrict__ ws_u,             // (T,D) fp32
    const int* __restrict__ flag,
    void* __restrict__ out)                     // (P,D)
{
    __shared__ __align__(16) float vsh[T * D];
    __shared__ __align__(16) float ush[T * D];
    __shared__ __align__(16) float gsh[2][2][R][D];   // [pair][s][r][d] 8 KB
    __shared__ __align__(16) float ysh[2][2][D];      // [pair][half][d] 2 KB

    const int f32  = *flag;
    const int tid  = threadIdx.x;
    const int wv   = tid >> 6;
    const int l    = tid & 63;
    const int pr   = wv >> 1;                   // pair within block
    const int s    = wv & 1;                    // side
    const int p    = blockIdx.x * 2 + pr;
    const int rsub = l >> 4;                    // quarter-wave
    const int ch   = l & 15;                    // 16B (8-elem) chunk within a row
    const int base = p * 2 * R * K + s * 64;    // flat (p, s, 0, 0)

    // Per-lane row ownership: lane l owns row j=l of side s -> (r=l>>4, k=l&15).
    const int nb  = nbr[base + l];
    const float dtv = ldE(dlt, (size_t)base + l, f32);
    const int tp  = types[nb];
    const int ns  = pairs[p * 2 + s];
    const int ts  = types[ns];

    const unsigned short* eu = (const unsigned short*)emb;

    // Pre-barrier hoist: first r's gathers + e_s row elements fly during the
    // LDS table fill + barrier.
    int snb[4];
    #pragma unroll
    for (int i = 0; i < 4; ++i) snb[i] = __shfl(nb, i * 4 + rsub, 64);
    uint4 cur[4] = {};
    float ee0, ee1;
    if (!f32) {
        #pragma unroll
        for (int i = 0; i < 4; ++i)
            cur[i] = *(const uint4*)(eu + (size_t)snb[i] * D + ch * 8);
        unsigned int w2 = *(const unsigned int*)(eu + (size_t)ns * D + 2 * l);
        ee0 = bf2f(w2 & 0xffffu); ee1 = bf2f(w2 >> 16);
    } else {
        float2 f2 = *(const float2*)((const float*)emb + (size_t)ns * D + 2 * l);
        ee0 = f2.x; ee1 = f2.y;
    }

    for (int i = tid; i < T * D; i += 256) { vsh[i] = ws_v[i]; ush[i] = ws_u[i]; }
    __syncthreads();

    // Side score e_s = emb[pair_s] . u_{type}: lane covers elems 2l, 2l+1.
    float es;
    {
        float a = ee0 * ush[ts * D + 2 * l] + ee1 * ush[ts * D + 2 * l + 1];
        #pragma unroll
        for (int off = 1; off <= 32; off <<= 1) a += __shfl_xor(a, off, 64);
        es = a;
    }

    if (!f32) {
        // ---- bf16 fast path: prefetch-pipelined r-loop ----
        uint4 nxt[4];
        #pragma unroll
        for (int r = 0; r < R; ++r) {
            float sdt[4]; int stp[4];
            #pragma unroll
            for (int i = 0; i < 4; ++i) {
                int srcl = r * 16 + i * 4 + rsub;
                sdt[i] = __shfl(dtv, srcl, 64);
                stp[i] = __shfl(tp,  srcl, 64);
            }
            if (r < 3) {   // issue next r's gathers before this r's VALU phase
                int snb2[4];
                #pragma unroll
                for (int i = 0; i < 4; ++i) snb2[i] = __shfl(nb, (r + 1) * 16 + i * 4 + rsub, 64);
                #pragma unroll
                for (int i = 0; i < 4; ++i)
                    nxt[i] = *(const uint4*)(eu + (size_t)snb2[i] * D + ch * 8);
            }
            // scores: e_n dot with v_{type}
            float ef[4];
            #pragma unroll
            for (int i = 0; i < 4; ++i) {
                const float* vp = vsh + stp[i] * D + ch * 8;
                float4 v0 = *(const float4*)vp;
                float4 v1 = *(const float4*)(vp + 4);
                float a = 0.f;
                a += bf2f(cur[i].x & 0xffffu) * v0.x + bf2f(cur[i].x >> 16) * v0.y;
                a += bf2f(cur[i].y & 0xffffu) * v0.z + bf2f(cur[i].y >> 16) * v0.w;
                a += bf2f(cur[i].z & 0xffffu) * v1.x + bf2f(cur[i].z >> 16) * v1.y;
                a += bf2f(cur[i].w & 0xffffu) * v1.z + bf2f(cur[i].w >> 16) * v1.w;
                #pragma unroll
                for (int off = 1; off <= 8; off <<= 1) a += __shfl_xor(a, off, 64);
                ef[i] = (a + es) * __expf(-sdt[i]);
            }
            // softmax over the 16 rows of (s, r)
            float m = fmaxf(fmaxf(ef[0], ef[1]), fmaxf(ef[2], ef[3]));
            m = fmaxf(m, __shfl_xor(m, 16, 64));
            m = fmaxf(m, __shfl_xor(m, 32, 64));
            float al[4], ssum = 0.f;
            #pragma unroll
            for (int i = 0; i < 4; ++i) { al[i] = __expf(ef[i] - m); ssum += al[i]; }
            ssum += __shfl_xor(ssum, 16, 64);
            ssum += __shfl_xor(ssum, 32, 64);
            float inv = 1.f / ssum;
            // alpha-weighted sum from the same registers
            float acc[8] = {0.f,0.f,0.f,0.f,0.f,0.f,0.f,0.f};
            #pragma unroll
            for (int i = 0; i < 4; ++i) {
                float a = al[i] * inv;
                acc[0] += a * bf2f(cur[i].x & 0xffffu); acc[1] += a * bf2f(cur[i].x >> 16);
                acc[2] += a * bf2f(cur[i].y & 0xffffu); acc[3] += a * bf2f(cur[i].y >> 16);
                acc[4] += a * bf2f(cur[i].z & 0xffffu); acc[5] += a * bf2f(cur[i].z >> 16);
                acc[6] += a * bf2f(cur[i].w & 0xffffu); acc[7] += a * bf2f(cur[i].w >> 16);
            }
            #pragma unroll
            for (int q = 0; q < 8; ++q) {
                acc[q] += __shfl_xor(acc[q], 16, 64);
                acc[q] += __shfl_xor(acc[q], 32, 64);
            }
            if (rsub == 0) {
                *(float4*)(&gsh[pr][s][r][ch * 8])     = make_float4(acc[0], acc[1], acc[2], acc[3]);
                *(float4*)(&gsh[pr][s][r][ch * 8 + 4]) = make_float4(acc[4], acc[5], acc[6], acc[7]);
            }
            #pragma unroll
            for (int i = 0; i < 4; ++i) cur[i] = nxt[i];
        }
    } else {
        // ---- fp32 fallback: reload-based (no rv[4][8] live across softmax;
        // fp32 emb is L3-resident so the second read is cheap) ----
        #pragma unroll
        for (int r = 0; r < R; ++r) {
            int snbL[4]; float sdt[4]; int stp[4];
            #pragma unroll
            for (int i = 0; i < 4; ++i) {
                int srcl = r * 16 + i * 4 + rsub;
                snbL[i] = __shfl(nb,  srcl, 64);
                sdt[i] = __shfl(dtv, srcl, 64);
                stp[i] = __shfl(tp,  srcl, 64);
            }
            float ef[4];
            #pragma unroll
            for (int i = 0; i < 4; ++i) {
                const float* vp = vsh + stp[i] * D + ch * 8;
                float rv[8];
                ld8(emb, (size_t)snbL[i] * D + ch * 8, 1, rv);
                float a = 0.f;
                #pragma unroll
                for (int q = 0; q < 8; ++q) a += rv[q] * vp[q];
                #pragma unroll
                for (int off = 1; off <= 8; off <<= 1) a += __shfl_xor(a, off, 64);
                ef[i] = (a + es) * __expf(-sdt[i]);
            }
            float m = fmaxf(fmaxf(ef[0], ef[1]), fmaxf(ef[2], ef[3]));
            m = fmaxf(m, __shfl_xor(m, 16, 64));
            m = fmaxf(m, __shfl_xor(m, 32, 64));
            float al[4], ssum = 0.f;
            #pragma unroll
            for (int i = 0; i < 4; ++i) { al[i] = __expf(ef[i] - m); ssum += al[i]; }
            ssum += __shfl_xor(ssum, 16, 64);
            ssum += __shfl_xor(ssum, 32, 64);
            float inv = 1.f / ssum;
            float acc[8] = {0.f,0.f,0.f,0.f,0.f,0.f,0.f,0.f};
            #pragma unroll
            for (int i = 0; i < 4; ++i) {
                float a = al[i] * inv;
                float rv[8];
                ld8(emb, (size_t)snbL[i] * D + ch * 8, 1, rv);
                #pragma unroll
                for (int q = 0; q < 8; ++q) acc[q] += a * rv[q];
            }
            #pragma unroll
            for (int q = 0; q < 8; ++q) {
                acc[q] += __shfl_xor(acc[q], 16, 64);
                acc[q] += __shfl_xor(acc[q], 32, 64);
            }
            if (rsub == 0) {
                *(float4*)(&gsh[pr][s][r][ch * 8])     = make_float4(acc[0], acc[1], acc[2], acc[3]);
                *(float4*)(&gsh[pr][s][r][ch * 8 + 4]) = make_float4(acc[4], acc[5], acc[6], acc[7]);
            }
        }
    }
    __syncthreads();

    // ---- Beta matvec: wave (pr, s) handles r in {2s, 2s+1}.
    // y[e] += sum_d (g0[r][d]+g1[r][d]) * W[r,d,e]; lane: e = ch*8+q, d-quarter = rsub.
    // d staggered per quarter so the 4 broadcast reads hit 4 distinct banks.
    float y[8] = {0.f,0.f,0.f,0.f,0.f,0.f,0.f,0.f};
    const unsigned short* Wu = (const unsigned short*)W_bw;
    #pragma unroll
    for (int rr = 0; rr < 2; ++rr) {
        const int r = s * 2 + rr;
        #pragma unroll 8
        for (int dd = 0; dd < 32; ++dd) {
            const int d = rsub * 32 + ((dd + 8 * rsub) & 31);
            float gd = gsh[pr][0][r][d] + gsh[pr][1][r][d];
            size_t wo = ((size_t)(r * D + d)) * D + ch * 8;
            if (!f32) {
                uint4 wr = *(const uint4*)(Wu + wo);
                y[0] += gd * bf2f(wr.x & 0xffffu); y[1] += gd * bf2f(wr.x >> 16);
                y[2] += gd * bf2f(wr.y & 0xffffu); y[3] += gd * bf2f(wr.y >> 16);
                y[4] += gd * bf2f(wr.z & 0xffffu); y[5] += gd * bf2f(wr.z >> 16);
                y[6] += gd * bf2f(wr.w & 0xffffu); y[7] += gd * bf2f(wr.w >> 16);
            } else {
                float wb[8]; ld8(W_bw, wo, 1, wb);
                #pragma unroll
                for (int q = 0; q < 8; ++q) y[q] += gd * wb[q];
            }
        }
    }
    #pragma unroll
    for (int q = 0; q < 8; ++q) {
        y[q] += __shfl_xor(y[q], 16, 64);
        y[q] += __shfl_xor(y[q], 32, 64);
    }
    if (rsub == 0) {
        *(float4*)(&ysh[pr][s][ch * 8])     = make_float4(y[0], y[1], y[2], y[3]);
        *(float4*)(&ysh[pr][s][ch * 8 + 4]) = make_float4(y[4], y[5], y[6], y[7]);
    }
    __syncthreads();

    // ---- Epilogue: waves with s==0, lanes rsub==0 (16 lanes -> 256B store).
    if (s == 0 && rsub == 0) {
        float bs[8] = {0.f,0.f,0.f,0.f,0.f,0.f,0.f,0.f};
        #pragma unroll
        for (int r = 0; r < R; ++r) {
            float bb[8]; ld8(W_bb, (size_t)r * D + ch * 8, f32, bb);
            #pragma unroll
            for (int q = 0; q < 8; ++q) bs[q] += bb[q];
        }
        float o[8];
        #pragma unroll
        for (int q = 0; q < 8; ++q) {
            int e = ch * 8 + q;
            float x = (ysh[pr][0][e] + ysh[pr][1][e] + 2.f * bs[q]) * 0.125f;
            o[q] = 1.f / (1.f + __expf(-x));
        }
        size_t ob = (size_t)p * D + ch * 8;
        if (f32) {
            *(float4*)((float*)out + ob)     = make_float4(o[0], o[1], o[2], o[3]);
            *(float4*)((float*)out + ob + 4) = make_float4(o[4], o[5], o[6], o[7]);
        } else {
            uint4 pk;
            pk.x = (unsigned int)f2bf(o[0]) | ((unsigned int)f2bf(o[1]) << 16);
            pk.y = (unsigned int)f2bf(o[2]) | ((unsigned int)f2bf(o[3]) << 16);
            pk.z = (unsigned int)f2bf(o[4]) | ((unsigned int)f2bf(o[5]) << 16);
            pk.w = (unsigned int)f2bf(o[6]) | ((unsigned int)f2bf(o[7]) << 16);
            *(uint4*)((unsigned short*)out + ob) = pk;
        }
    }
}

extern "C" void kernel_launch(void* const* d_in, const int* in_sizes, int n_in,
                              void* d_out, int out_size, void* d_ws, size_t ws_size,
                              hipStream_t stream) {
    const void* emb    = d_in[0];
    const int*  pairs  = (const int*)d_in[1];
    const int*  types  = (const int*)d_in[2];
    const int*  nbr    = (const int*)d_in[3];
    const void* dlt    = d_in[4];
    const void* W_phi  = d_in[5];
    const void* W_zeta = d_in[6];
    const void* W_bw   = d_in[7];
    const void* W_bb   = d_in[8];

    int*   flag = (int*)d_ws;                        // bytes [0,256)
    float* ws_v = (float*)d_ws + 64;                 // 384 floats
    float* ws_u = ws_v + T * D;                      // 384 floats

    prep_kernel<<<dim3(T), dim3(128), 0, stream>>>((const unsigned short*)emb,
                                                   W_phi, W_zeta, flag, ws_v, ws_u);
    fused_all<<<dim3(P / 2), dim3(256), 0, stream>>>(emb, pairs, types, nbr, dlt,
                                                     W_bw, W_bb, ws_v, ws_u, flag, d_out);
}

// Round 8
// 251.644 us; speedup vs baseline: 1.2036x; 1.1623x over previous
//
#include <hip/hip_runtime.h>
#include <hip/hip_bf16.h>

#define NN 200000
#define D 128
#define P 4096
#define R 4
#define T 3
#define K 16

__device__ __forceinline__ float bf2f(unsigned int u) {
    union { unsigned int i; float f; } c;
    c.i = u << 16;
    return c.f;
}
__device__ __forceinline__ unsigned short f2bf(float x) {  // RNE
    union { float f; unsigned int i; } c; c.f = x;
    unsigned int r = c.i + 0x7FFFu + ((c.i >> 16) & 1u);
    return (unsigned short)(r >> 16);
}
__device__ __forceinline__ float ldE(const void* p, size_t i, int f32) {
    return f32 ? ((const float*)p)[i] : bf2f(((const unsigned short*)p)[i]);
}
__device__ __forceinline__ void ld8(const void* p, size_t off, int f32, float* o) {
    if (f32) {
        const float* q = (const float*)p + off;
        float4 a = *(const float4*)q;
        float4 b = *(const float4*)(q + 4);
        o[0]=a.x; o[1]=a.y; o[2]=a.z; o[3]=a.w;
        o[4]=b.x; o[5]=b.y; o[6]=b.z; o[7]=b.w;
    } else {
        uint4 r = *(const uint4*)((const unsigned short*)p + off);
        o[0]=bf2f(r.x & 0xffffu); o[1]=bf2f(r.x >> 16);
        o[2]=bf2f(r.y & 0xffffu); o[3]=bf2f(r.y >> 16);
        o[4]=bf2f(r.z & 0xffffu); o[5]=bf2f(r.z >> 16);
        o[6]=bf2f(r.w & 0xffffu); o[7]=bf2f(r.w >> 16);
    }
}

// Prep kernel: per-block dtype detection + v_t/u_t precompute. Grid = T blocks x 128.
__global__ void prep_kernel(const unsigned short* __restrict__ emb_u,
                            const void* __restrict__ W_phi,
                            const void* __restrict__ W_zeta,
                            int* __restrict__ gflag,
                            float* __restrict__ ws_v, float* __restrict__ ws_u) {
    __shared__ int sbad[2];
    const int tid = threadIdx.x;          // 0..127
    const int t   = blockIdx.x;           // 0..T-1
    // dtype sniff: even-index ushorts of bf16(N(0,1)) have small exponents;
    // of fp32 they are random mantissa bits -> uniform exponents. (validated r2-r5)
    int bad = 0;
    #pragma unroll
    for (int i = 0; i < 4; ++i) {
        unsigned short u = emb_u[(size_t)(blockIdx.x * 512 + tid * 4 + i) * 2 * 97];
        unsigned int e = (u >> 7) & 0xFFu;
        if (e >= 147u) bad = 1;
    }
    int anyb = __any(bad) ? 1 : 0;
    if ((tid & 63) == 0) sbad[tid >> 6] = anyb;
    __syncthreads();
    const int f32 = sbad[0] | sbad[1];
    if (t == 0 && tid == 0) *gflag = f32;

    const int d = tid;
    const size_t rb = (size_t)(t * D + d) * D;
    float av = 0.f, au = 0.f;
    for (int e = 0; e < D; e += 8) {
        float w[8], zn[8], zs[8];
        ld8(W_phi, rb + e, f32, w);
        ld8(W_zeta, e, f32, zn);
        ld8(W_zeta, D + e, f32, zs);
        #pragma unroll
        for (int q = 0; q < 8; ++q) { av += w[q] * zn[q]; au += w[q] * zs[q]; }
    }
    ws_v[t * D + d] = av;
    ws_u[t * D + d] = au;
}

// Fused kernel v7: v1's proven structure (block = 2 pairs x 2 sides; wave =
// (pair, side); r-loop with depth-1 gather prefetch; (256,4) -> VGPR cap 64,
// 52-60 used, no spill). NEW: cooperative-r beta matvec -- wave wv handles
// r = wv for BOTH pairs (y0/y1 accumulators), so each W_bw row is read exactly
// once per block: 256 KB -> 128 KB L2 reads per block (512 -> 256 MB total),
// beta VMEM instrs per wave 64 -> 32.
// Launch-bounds model (validated r2-r6): VGPR cap = 256/arg regardless of
// block size ((512,8)->32, (256,8)->32, (512,4)->64, (512,3)->~85). 8 waves/EU
// is unreachable without spill for this body; (256,4) is the sweet spot.
__global__ __launch_bounds__(256, 4) void fused_all(
    const void* __restrict__ emb,               // (N,D)
    const int* __restrict__ pairs,              // (P,2)
    const int* __restrict__ types,              // (N,)
    const int* __restrict__ nbr,                // (P,2,R,K)
    const void* __restrict__ dlt,               // (P,2,R,K)
    const void* __restrict__ W_bw,              // (R,D,D)
    const void* __restrict__ W_bb,              // (R,D)
    const float* __restrict__ ws_v,             // (T,D) fp32
    const float* __restrict__ ws_u,             // (T,D) fp32
    const int* __restrict__ flag,
    void* __restrict__ out)                     // (P,D)
{
    __shared__ __align__(16) float vsh[T * D];
    __shared__ __align__(16) float ush[T * D];
    __shared__ __align__(16) float gsh[2][2][R][D];   // [pair][s][r][d] 8 KB
    __shared__ __align__(16) float ysh[2][R][D];      // [pair][r][d]    4 KB

    const int f32  = *flag;
    const int tid  = threadIdx.x;
    const int wv   = tid >> 6;
    const int l    = tid & 63;
    const int pr   = wv >> 1;                   // pair within block
    const int s    = wv & 1;                    // side
    const int p    = blockIdx.x * 2 + pr;
    const int rsub = l >> 4;                    // quarter-wave
    const int ch   = l & 15;                    // 16B (8-elem) chunk within a row
    const int base = p * 2 * R * K + s * 64;    // flat (p, s, 0, 0)

    // Per-lane row ownership: lane l owns row j=l of side s -> (r=l>>4, k=l&15).
    const int nb  = nbr[base + l];
    const float dtv = ldE(dlt, (size_t)base + l, f32);
    const int tp  = types[nb];
    const int ns  = pairs[p * 2 + s];
    const int ts  = types[ns];

    const unsigned short* eu = (const unsigned short*)emb;

    // Pre-barrier hoist: first r's gathers + e_s row elements fly during the
    // LDS table fill + barrier.
    int snb[4];
    #pragma unroll
    for (int i = 0; i < 4; ++i) snb[i] = __shfl(nb, i * 4 + rsub, 64);
    uint4 cur[4] = {};
    float ee0, ee1;
    if (!f32) {
        #pragma unroll
        for (int i = 0; i < 4; ++i)
            cur[i] = *(const uint4*)(eu + (size_t)snb[i] * D + ch * 8);
        unsigned int w2 = *(const unsigned int*)(eu + (size_t)ns * D + 2 * l);
        ee0 = bf2f(w2 & 0xffffu); ee1 = bf2f(w2 >> 16);
    } else {
        float2 f2 = *(const float2*)((const float*)emb + (size_t)ns * D + 2 * l);
        ee0 = f2.x; ee1 = f2.y;
    }

    for (int i = tid; i < T * D; i += 256) { vsh[i] = ws_v[i]; ush[i] = ws_u[i]; }
    __syncthreads();

    // Side score e_s = emb[pair_s] . u_{type}: lane covers elems 2l, 2l+1.
    float es;
    {
        float a = ee0 * ush[ts * D + 2 * l] + ee1 * ush[ts * D + 2 * l + 1];
        #pragma unroll
        for (int off = 1; off <= 32; off <<= 1) a += __shfl_xor(a, off, 64);
        es = a;
    }

    if (!f32) {
        // ---- bf16 fast path: prefetch-pipelined r-loop ----
        uint4 nxt[4];
        #pragma unroll
        for (int r = 0; r < R; ++r) {
            float sdt[4]; int stp[4];
            #pragma unroll
            for (int i = 0; i < 4; ++i) {
                int srcl = r * 16 + i * 4 + rsub;
                sdt[i] = __shfl(dtv, srcl, 64);
                stp[i] = __shfl(tp,  srcl, 64);
            }
            if (r < 3) {   // issue next r's gathers before this r's VALU phase
                int snb2[4];
                #pragma unroll
                for (int i = 0; i < 4; ++i) snb2[i] = __shfl(nb, (r + 1) * 16 + i * 4 + rsub, 64);
                #pragma unroll
                for (int i = 0; i < 4; ++i)
                    nxt[i] = *(const uint4*)(eu + (size_t)snb2[i] * D + ch * 8);
            }
            // scores: e_n dot with v_{type}
            float ef[4];
            #pragma unroll
            for (int i = 0; i < 4; ++i) {
                const float* vp = vsh + stp[i] * D + ch * 8;
                float4 v0 = *(const float4*)vp;
                float4 v1 = *(const float4*)(vp + 4);
                float a = 0.f;
                a += bf2f(cur[i].x & 0xffffu) * v0.x + bf2f(cur[i].x >> 16) * v0.y;
                a += bf2f(cur[i].y & 0xffffu) * v0.z + bf2f(cur[i].y >> 16) * v0.w;
                a += bf2f(cur[i].z & 0xffffu) * v1.x + bf2f(cur[i].z >> 16) * v1.y;
                a += bf2f(cur[i].w & 0xffffu) * v1.z + bf2f(cur[i].w >> 16) * v1.w;
                #pragma unroll
                for (int off = 1; off <= 8; off <<= 1) a += __shfl_xor(a, off, 64);
                ef[i] = (a + es) * __expf(-sdt[i]);
            }
            // softmax over the 16 rows of (s, r)
            float m = fmaxf(fmaxf(ef[0], ef[1]), fmaxf(ef[2], ef[3]));
            m = fmaxf(m, __shfl_xor(m, 16, 64));
            m = fmaxf(m, __shfl_xor(m, 32, 64));
            float al[4], ssum = 0.f;
            #pragma unroll
            for (int i = 0; i < 4; ++i) { al[i] = __expf(ef[i] - m); ssum += al[i]; }
            ssum += __shfl_xor(ssum, 16, 64);
            ssum += __shfl_xor(ssum, 32, 64);
            float inv = 1.f / ssum;
            // alpha-weighted sum from the same registers
            float acc[8] = {0.f,0.f,0.f,0.f,0.f,0.f,0.f,0.f};
            #pragma unroll
            for (int i = 0; i < 4; ++i) {
                float a = al[i] * inv;
                acc[0] += a * bf2f(cur[i].x & 0xffffu); acc[1] += a * bf2f(cur[i].x >> 16);
                acc[2] += a * bf2f(cur[i].y & 0xffffu); acc[3] += a * bf2f(cur[i].y >> 16);
                acc[4] += a * bf2f(cur[i].z & 0xffffu); acc[5] += a * bf2f(cur[i].z >> 16);
                acc[6] += a * bf2f(cur[i].w & 0xffffu); acc[7] += a * bf2f(cur[i].w >> 16);
            }
            #pragma unroll
            for (int q = 0; q < 8; ++q) {
                acc[q] += __shfl_xor(acc[q], 16, 64);
                acc[q] += __shfl_xor(acc[q], 32, 64);
            }
            if (rsub == 0) {
                *(float4*)(&gsh[pr][s][r][ch * 8])     = make_float4(acc[0], acc[1], acc[2], acc[3]);
                *(float4*)(&gsh[pr][s][r][ch * 8 + 4]) = make_float4(acc[4], acc[5], acc[6], acc[7]);
            }
            #pragma unroll
            for (int i = 0; i < 4; ++i) cur[i] = nxt[i];
        }
    } else {
        // ---- fp32 fallback: reload-based (no rv[4][8] live across softmax;
        // fp32 emb is L3-resident so the second read is cheap) ----
        #pragma unroll
        for (int r = 0; r < R; ++r) {
            int snbL[4]; float sdt[4]; int stp[4];
            #pragma unroll
            for (int i = 0; i < 4; ++i) {
                int srcl = r * 16 + i * 4 + rsub;
                snbL[i] = __shfl(nb,  srcl, 64);
                sdt[i] = __shfl(dtv, srcl, 64);
                stp[i] = __shfl(tp,  srcl, 64);
            }
            float ef[4];
            #pragma unroll
            for (int i = 0; i < 4; ++i) {
                const float* vp = vsh + stp[i] * D + ch * 8;
                float rv[8];
                ld8(emb, (size_t)snbL[i] * D + ch * 8, 1, rv);
                float a = 0.f;
                #pragma unroll
                for (int q = 0; q < 8; ++q) a += rv[q] * vp[q];
                #pragma unroll
                for (int off = 1; off <= 8; off <<= 1) a += __shfl_xor(a, off, 64);
                ef[i] = (a + es) * __expf(-sdt[i]);
            }
            float m = fmaxf(fmaxf(ef[0], ef[1]), fmaxf(ef[2], ef[3]));
            m = fmaxf(m, __shfl_xor(m, 16, 64));
            m = fmaxf(m, __shfl_xor(m, 32, 64));
            float al[4], ssum = 0.f;
            #pragma unroll
            for (int i = 0; i < 4; ++i) { al[i] = __expf(ef[i] - m); ssum += al[i]; }
            ssum += __shfl_xor(ssum, 16, 64);
            ssum += __shfl_xor(ssum, 32, 64);
            float inv = 1.f / ssum;
            float acc[8] = {0.f,0.f,0.f,0.f,0.f,0.f,0.f,0.f};
            #pragma unroll
            for (int i = 0; i < 4; ++i) {
                float a = al[i] * inv;
                float rv[8];
                ld8(emb, (size_t)snbL[i] * D + ch * 8, 1, rv);
                #pragma unroll
                for (int q = 0; q < 8; ++q) acc[q] += a * rv[q];
            }
            #pragma unroll
            for (int q = 0; q < 8; ++q) {
                acc[q] += __shfl_xor(acc[q], 16, 64);
                acc[q] += __shfl_xor(acc[q], 32, 64);
            }
            if (rsub == 0) {
                *(float4*)(&gsh[pr][s][r][ch * 8])     = make_float4(acc[0], acc[1], acc[2], acc[3]);
                *(float4*)(&gsh[pr][s][r][ch * 8 + 4]) = make_float4(acc[4], acc[5], acc[6], acc[7]);
            }
        }
    }
    __syncthreads();

    // ---- Beta matvec (cooperative-r): wave wv handles r = wv for BOTH pairs.
    // Each W_bw row is read exactly once per block (128 KB total, was 256 KB).
    // y0/y1: partial y[e] for pair 0 / pair 1; lane: e = ch*8+q, d-quarter = rsub.
    // d staggered per quarter so the 4 broadcast gsh reads hit 4 distinct banks.
    float y0[8] = {0.f,0.f,0.f,0.f,0.f,0.f,0.f,0.f};
    float y1[8] = {0.f,0.f,0.f,0.f,0.f,0.f,0.f,0.f};
    {
        const int rb = wv;                      // this wave's r
        const unsigned short* Wu = (const unsigned short*)W_bw;
        #pragma unroll 8
        for (int dd = 0; dd < 32; ++dd) {
            const int d = rsub * 32 + ((dd + 8 * rsub) & 31);
            const float g0 = gsh[0][0][rb][d] + gsh[0][1][rb][d];
            const float g1 = gsh[1][0][rb][d] + gsh[1][1][rb][d];
            const size_t wo = ((size_t)(rb * D + d)) * D + ch * 8;
            if (!f32) {
                uint4 wr = *(const uint4*)(Wu + wo);
                float w;
                w = bf2f(wr.x & 0xffffu); y0[0] += g0 * w; y1[0] += g1 * w;
                w = bf2f(wr.x >> 16);     y0[1] += g0 * w; y1[1] += g1 * w;
                w = bf2f(wr.y & 0xffffu); y0[2] += g0 * w; y1[2] += g1 * w;
                w = bf2f(wr.y >> 16);     y0[3] += g0 * w; y1[3] += g1 * w;
                w = bf2f(wr.z & 0xffffu); y0[4] += g0 * w; y1[4] += g1 * w;
                w = bf2f(wr.z >> 16);     y0[5] += g0 * w; y1[5] += g1 * w;
                w = bf2f(wr.w & 0xffffu); y0[6] += g0 * w; y1[6] += g1 * w;
                w = bf2f(wr.w >> 16);     y0[7] += g0 * w; y1[7] += g1 * w;
            } else {
                float wb[8]; ld8(W_bw, wo, 1, wb);
                #pragma unroll
                for (int q = 0; q < 8; ++q) { y0[q] += g0 * wb[q]; y1[q] += g1 * wb[q]; }
            }
        }
        #pragma unroll
        for (int q = 0; q < 8; ++q) {
            y0[q] += __shfl_xor(y0[q], 16, 64); y0[q] += __shfl_xor(y0[q], 32, 64);
            y1[q] += __shfl_xor(y1[q], 16, 64); y1[q] += __shfl_xor(y1[q], 32, 64);
        }
        if (rsub == 0) {
            *(float4*)(&ysh[0][rb][ch * 8])     = make_float4(y0[0], y0[1], y0[2], y0[3]);
            *(float4*)(&ysh[0][rb][ch * 8 + 4]) = make_float4(y0[4], y0[5], y0[6], y0[7]);
            *(float4*)(&ysh[1][rb][ch * 8])     = make_float4(y1[0], y1[1], y1[2], y1[3]);
            *(float4*)(&ysh[1][rb][ch * 8 + 4]) = make_float4(y1[4], y1[5], y1[6], y1[7]);
        }
    }
    __syncthreads();

    // ---- Epilogue: waves with s==0 (wv 0 -> pr 0, wv 2 -> pr 1), lanes rsub==0.
    if (s == 0 && rsub == 0) {
        float bs[8] = {0.f,0.f,0.f,0.f,0.f,0.f,0.f,0.f};
        #pragma unroll
        for (int r = 0; r < R; ++r) {
            float bb[8]; ld8(W_bb, (size_t)r * D + ch * 8, f32, bb);
            #pragma unroll
            for (int q = 0; q < 8; ++q) bs[q] += bb[q];
        }
        float o[8];
        #pragma unroll
        for (int q = 0; q < 8; ++q) {
            int e = ch * 8 + q;
            float x = (ysh[pr][0][e] + ysh[pr][1][e] + ysh[pr][2][e] + ysh[pr][3][e]
                       + 2.f * bs[q]) * 0.125f;
            o[q] = 1.f / (1.f + __expf(-x));
        }
        size_t ob = (size_t)p * D + ch * 8;
        if (f32) {
            *(float4*)((float*)out + ob)     = make_float4(o[0], o[1], o[2], o[3]);
            *(float4*)((float*)out + ob + 4) = make_float4(o[4], o[5], o[6], o[7]);
        } else {
            uint4 pk;
            pk.x = (unsigned int)f2bf(o[0]) | ((unsigned int)f2bf(o[1]) << 16);
            pk.y = (unsigned int)f2bf(o[2]) | ((unsigned int)f2bf(o[3]) << 16);
            pk.z = (unsigned int)f2bf(o[4]) | ((unsigned int)f2bf(o[5]) << 16);
            pk.w = (unsigned int)f2bf(o[6]) | ((unsigned int)f2bf(o[7]) << 16);
            *(uint4*)((unsigned short*)out + ob) = pk;
        }
    }
}

extern "C" void kernel_launch(void* const* d_in, const int* in_sizes, int n_in,
                              void* d_out, int out_size, void* d_ws, size_t ws_size,
                              hipStream_t stream) {
    const void* emb    = d_in[0];
    const int*  pairs  = (const int*)d_in[1];
    const int*  types  = (const int*)d_in[2];
    const int*  nbr    = (const int*)d_in[3];
    const void* dlt    = d_in[4];
    const void* W_phi  = d_in[5];
    const void* W_zeta = d_in[6];
    const void* W_bw   = d_in[7];
    const void* W_bb   = d_in[8];

    int*   flag = (int*)d_ws;                        // bytes [0,256)
    float* ws_v = (float*)d_ws + 64;                 // 384 floats
    float* ws_u = ws_v + T * D;                      // 384 floats

    prep_kernel<<<dim3(T), dim3(128), 0, stream>>>((const unsigned short*)emb,
                                                   W_phi, W_zeta, flag, ws_v, ws_u);
    fused_all<<<dim3(P / 2), dim3(256), 0, stream>>>(emb, pairs, types, nbr, dlt,
                                                     W_bw, W_bb, ws_v, ws_u, flag, d_out);
}